// Round 5
// baseline (245.735 us; speedup 1.0000x reference)
//
#include <hip/hip_runtime.h>

// Layout (established rounds 0-4 of prior session):
//   d_in[0] tokens : int32, R=256 x L=512
//   d_in[1] lprobs : fp32,  R=256 x V=128000 (131 MB)
//   d_in[2] bsz, d_in[3] beam_size, d_in[4] step : 1-elem int arrays
//   d_out  : fp32, same shape as lprobs
//
// Correctness model (hard-won, do not regress):
//   * Harness compares through bfloat16. fp32 -FLT_MAX rounds UP to bf16
//     -inf -> (-inf)-(-inf)=nan -> fail. Sentinel 0xFF7F0000 = most
//     negative finite bf16: finite in fp32 AND after bf16 rounding.
//   * Every byte of d_out written deterministically each call.
//   * Ban writes are idempotent; ban kernel is stream-ordered AFTER the
//     copy kernel (no intra-kernel ordering assumptions).
//
// Timing model (rounds 2-4 post-mortems):
//   * Timed window ~230-243 us = harness re-poison fill (524 MB @ 6.5
//     TB/s, ~80 us) + restores + our kernels. Controllable = our side.
//   * CHUNK-OWNERSHIP copy capped at 2.47 TB/s HBM (80 us) in rounds
//     3-4 regardless of batching depth (compiler re-interleaved batches:
//     VGPR=28 proves it). MLP arithmetic rules out per-wave depth as the
//     limiter. Theory: 64 KB-aligned per-block chunks phase-correlate
//     addresses across blocks -> HBM channel convoying. Known-fast
//     patterns on this chip are FLAT grid-stride (fill 6.5 TB/s, m13
//     float4 copy 6.29 TB/s).
//   * Round 0's flat copy used 32000 blocks x ONE float4/thread ->
//     block-churn-bound. This round: flat grid-stride, 2048 blocks
//     looping ~16x, 4 independent float4s per iteration.
//   * Non-temporal hints regressed (round 2). Do not reintroduce.

#define SENTINEL_BITS 0xFF7F0000u
#define NGRAM_N       3
#define THREADS       256

typedef float f32x4 __attribute__((ext_vector_type(4)));

// Kernel A: flat grid-stride float4 copy (m13 pattern, de-phased
// addresses), 4 independent copies per iteration, all indices static.
__global__ __launch_bounds__(THREADS)
void ngram_copy_kernel(const float* __restrict__ in,
                       float* __restrict__ out,
                       long n)
{
    const long n4     = n >> 2;
    const long stride = (long)gridDim.x * THREADS;
    const f32x4* __restrict__ in4  = (const f32x4*)in;
    f32x4* __restrict__       out4 = (f32x4*)out;

    long k = (long)blockIdx.x * THREADS + threadIdx.x;
    for (; k + 3 * stride < n4; k += 4 * stride) {
        f32x4 a = in4[k];
        f32x4 b = in4[k + stride];
        f32x4 c = in4[k + 2 * stride];
        f32x4 d = in4[k + 3 * stride];
        out4[k]              = a;
        out4[k + stride]     = b;
        out4[k + 2 * stride] = c;
        out4[k + 3 * stride] = d;
    }
    for (; k < n4; k += stride) out4[k] = in4[k];

    // scalar tail, < 4 elements (none at bench shape; deterministic)
    const long base = n4 << 2;
    if (blockIdx.x == 0 && (long)threadIdx.x < (n - base))
        out[base + threadIdx.x] = in[base + threadIdx.x];
}

// Kernel B: per-row n-gram ban, NGRAM=3. One block per row (grid-strided).
// Stream-ordered after kernel A; sentinel writes idempotent.
__global__ __launch_bounds__(THREADS)
void ngram_ban_kernel(const int* __restrict__ tokens,
                      float* __restrict__ out,
                      const int* __restrict__ step_ptr,
                      int tokens_count, int lprobs_count)
{
    const int n = NGRAM_N;
    const int step = *step_ptr;
    if (step + 2 - n < 0) return;          // reference early-out
    const int L = step + 1;
    if (L <= 0) return;
    const int R = tokens_count / L;
    if (R <= 0) return;
    const int V = lprobs_count / R;
    if (V <= 0) return;
    const int W = L - n + 1;
    const int p_start = step + 2 - n;      // prefix = trow[p_start..p_start+1]

    const float sentinel = __uint_as_float(SENTINEL_BITS);

    for (int r = blockIdx.x; r < R; r += gridDim.x) {
        const int* trow = tokens + (size_t)r * L;   // 2 KB, L2-hot
        const int p0 = trow[p_start];
        const int p1 = trow[p_start + 1];
        float* orow = out + (size_t)r * V;
        for (int w = threadIdx.x; w < W; w += blockDim.x) {
            if (trow[w] == p0 && trow[w + 1] == p1) {
                const int banned = trow[w + 2];
                if (banned >= 0 && banned < V)
                    orow[banned] = sentinel;        // idempotent
            }
        }
    }
}

extern "C" void kernel_launch(void* const* d_in, const int* in_sizes, int n_in,
                              void* d_out, int out_size, void* d_ws, size_t ws_size,
                              hipStream_t stream) {
    const int*   tokens   = (const int*)d_in[0];
    const float* lprobs   = (const float*)d_in[1];
    const int*   step_ptr = (const int*)d_in[4];   // bsz/beam unused (derived)
    float*       out      = (float*)d_out;

    const long n = (long)out_size;                 // R * V fp32 elements

    // Copy: 2048 blocks (8/CU, 32 waves/CU), each looping ~16 iterations
    // at the bench shape -> no block churn, de-phased flat addressing.
    int copy_blocks = 2048;
    long max_useful = (n / 4 + THREADS - 1) / THREADS;
    if (max_useful < copy_blocks) copy_blocks = (int)(max_useful > 0 ? max_useful : 1);

    ngram_copy_kernel<<<copy_blocks, THREADS, 0, stream>>>(lprobs, out, n);

    // Ban: one block per row (256 rows at bench shape), tiny.
    ngram_ban_kernel<<<256, THREADS, 0, stream>>>(
        tokens, out, step_ptr, in_sizes[0], in_sizes[1]);
}

// Round 8
// 239.604 us; speedup vs baseline: 1.0256x; 1.0256x over previous
//
#include <hip/hip_runtime.h>

// Layout (established rounds 0-4 of prior session):
//   d_in[0] tokens : int32, R=256 x L=512
//   d_in[1] lprobs : fp32,  R=256 x V=128000 (131 MB)
//   d_in[2] bsz, d_in[3] beam_size, d_in[4] step : 1-elem int arrays
//   d_out  : fp32, same shape as lprobs
//
// Correctness model (hard-won, do not regress):
//   * Harness compares through bfloat16. fp32 -FLT_MAX rounds UP to bf16
//     -inf -> (-inf)-(-inf)=nan -> fail. Sentinel 0xFF7F0000 = most
//     negative finite bf16: finite in fp32 AND after bf16 rounding.
//   * Every byte of d_out written deterministically each call.
//   * Ban writes idempotent; ban kernel stream-ordered AFTER copy.
//
// Timing model (rounds 2-5 post-mortems):
//   * Timed window = harness re-poison fill (524 MB @ 6.5 TB/s, ~80 us)
//     + restores + our kernels. Controllable = our kernels only.
//   * Copy rate INVARIANT at ~80 us / 2.45 TB/s HBM (3.27 TB/s effective)
//     across: chunk-ownership, 8-deep batch (compiler re-interleaved,
//     VGPR=28), flat 2048-block loop. All LOOPED structures.
//   * Write-only fill: 6.5 TB/s same window. m13 float4 copy: 6.29 TB/s.
//     => not a platform cap; shared cause = loop-carried store->load
//     serialization capping outstanding reads per wave.
//   * Round 0's ONE-SHOT copy (one float4/thread, 32000 blocks) is the
//     only unprofiled structure and matches best-ever e2e (230.9).
//   * Non-temporal hints regressed (round 2). Do not reintroduce.
//   * Rounds 6-7: infra failures (container died twice each) -- this is
//     the UNCHANGED resubmission of the round-5 one-shot kernel. If a
//     third identical run dies, treat as kernel-induced and restructure.
//
// Structure: ONE-SHOT copy, 2 float4/thread, loads-before-stores, wave
//   exits after stores (wave-slot turnover sustains read concurrency).

#define SENTINEL_BITS 0xFF7F0000u
#define NGRAM_N       3
#define THREADS       256

typedef float f32x4 __attribute__((ext_vector_type(4)));

// Kernel A: one-shot copy. Thread t copies float4 #t and #(t+half).
// Both loads issue before both stores (2 KB in flight/wave), then the
// wave exits -- no loop-carried dependence anywhere.
__global__ __launch_bounds__(THREADS)
void ngram_copy_kernel(const float* __restrict__ in,
                       float* __restrict__ out,
                       long n)
{
    const long n4   = n >> 2;
    const long half = n4 >> 1;
    const f32x4* __restrict__ in4  = (const f32x4*)in;
    f32x4* __restrict__       out4 = (f32x4*)out;

    const long i = (long)blockIdx.x * THREADS + threadIdx.x;
    if (i < half) {
        f32x4 a = in4[i];
        f32x4 b = in4[i + half];
        out4[i]        = a;
        out4[i + half] = b;
    }

    // leftovers: odd float4 (when n4 is odd) + scalar tail (n & 3).
    // None at the bench shape; block 0 handles them deterministically.
    if (blockIdx.x == 0) {
        const long odd = 2 * half;               // == n4-1 iff n4 odd
        if (threadIdx.x == 0 && odd < n4) out4[odd] = in4[odd];
        const long base = n4 << 2;
        const long rem  = n - base;              // 0..3
        if ((long)threadIdx.x < rem)
            out[base + threadIdx.x] = in[base + threadIdx.x];
    }
}

// Kernel B: per-row n-gram ban, NGRAM=3. One block per row (grid-strided).
// Stream-ordered after kernel A; sentinel writes idempotent.
__global__ __launch_bounds__(THREADS)
void ngram_ban_kernel(const int* __restrict__ tokens,
                      float* __restrict__ out,
                      const int* __restrict__ step_ptr,
                      int tokens_count, int lprobs_count)
{
    const int n = NGRAM_N;
    const int step = *step_ptr;
    if (step + 2 - n < 0) return;          // reference early-out
    const int L = step + 1;
    if (L <= 0) return;
    const int R = tokens_count / L;
    if (R <= 0) return;
    const int V = lprobs_count / R;
    if (V <= 0) return;
    const int W = L - n + 1;
    const int p_start = step + 2 - n;      // prefix = trow[p_start..p_start+1]

    const float sentinel = __uint_as_float(SENTINEL_BITS);

    for (int r = blockIdx.x; r < R; r += gridDim.x) {
        const int* trow = tokens + (size_t)r * L;   // 2 KB, L2-hot
        const int p0 = trow[p_start];
        const int p1 = trow[p_start + 1];
        float* orow = out + (size_t)r * V;
        for (int w = threadIdx.x; w < W; w += blockDim.x) {
            if (trow[w] == p0 && trow[w + 1] == p1) {
                const int banned = trow[w + 2];
                if (banned >= 0 && banned < V)
                    orow[banned] = sentinel;        // idempotent
            }
        }
    }
}

extern "C" void kernel_launch(void* const* d_in, const int* in_sizes, int n_in,
                              void* d_out, int out_size, void* d_ws, size_t ws_size,
                              hipStream_t stream) {
    const int*   tokens   = (const int*)d_in[0];
    const float* lprobs   = (const float*)d_in[1];
    const int*   step_ptr = (const int*)d_in[4];   // bsz/beam unused (derived)
    float*       out      = (float*)d_out;

    const long n = (long)out_size;                 // R * V fp32 elements

    // One-shot grid: half the float4 count, one thread each.
    // Bench shape: half = 4,096,000 -> 16000 blocks.
    long half = (n >> 2) >> 1;
    long blocks = (half + THREADS - 1) / THREADS;
    if (blocks > 65535) blocks = 65535;            // (not hit at bench shape)
    if (blocks < 1)     blocks = 1;

    ngram_copy_kernel<<<(int)blocks, THREADS, 0, stream>>>(lprobs, out, n);

    // Ban: one block per row (256 rows at bench shape), tiny.
    ngram_ban_kernel<<<256, THREADS, 0, stream>>>(
        tokens, out, step_ptr, in_sizes[0], in_sizes[1]);
}